// Round 10
// baseline (517.267 us; speedup 1.0000x reference)
//
#include <hip/hip_runtime.h>
#include <hip/hip_cooperative_groups.h>

namespace cg = cooperative_groups;

#define B_ 4
#define NB_ 131072
#define K_ 32
#define N_ (B_*NB_)
#define BK_ (B_*K_)        // 128
#define NBLK 256           // grid: 1 block per CU, co-resident by construction
#define NTHR 1024
#define PPB  (N_/NBLK)     // 2048 points per block
#define BPB  (NBLK/B_)     // 64 blocks per batch

// ws float layout (no zeroing needed; every slot plain-stored each call):
//   acc  [5*K_][NBLK]   : transposed per-block partials (row t, col block)
//   fin  [6][BK_]       : finalized cx,cy,cz,sig_mean,inv_cnt,inv2s2
//   part [NBLK][4]      : per-block partials (msum,smooth,seed,acc)
#define ACC_OFF  0
#define FIN_OFF  (5*K_*NBLK)             // 40960
#define PART_OFF (FIN_OFF + 6*BK_)       // 41728

__global__ __launch_bounds__(NTHR) void k_all(
    const float4* __restrict__ emb, const float* __restrict__ seedp,
    const float* __restrict__ labels, float* __restrict__ ws,
    float* __restrict__ out)
{
    cg::grid_group grid = cg::this_grid();
    int g = blockIdx.x;
    int tid = threadIdx.x;
    int b = g / BPB;                 // batch of this block

    __shared__ float sacc[4][5*K_];  // 4 replicas: 4 waves share each
    __shared__ float s_raw[5*K_];
    __shared__ float4 s_c4[K_];      // {cx,cy,cz,inv2s2}
    __shared__ float s_sig[K_], s_inv[K_];
    __shared__ float sred[16][4];
    __shared__ float S[16];

    // ================= phase 1: cluster accumulation =================
    if (tid < 4*5*K_) ((float*)sacc)[tid] = 0.f;
    __syncthreads();
    int rep = (tid >> 6) & 3;
    #pragma unroll
    for (int it = 0; it < PPB/NTHR; ++it) {
        int n = g*PPB + it*NTHR + tid;
        float4 e = emb[n];
        const float* lr = labels + (size_t)n*6;
        float c1 = lr[1];
        float2 c23 = *reinterpret_cast<const float2*>(lr + 2);
        int inst = ((int)lr[5]) & 31;
        float cex = e.x + (c1    - 384.f)/384.f;
        float cey = e.y + (c23.x - 384.f)/384.f;
        float cez = e.z + (c23.y - 384.f)/384.f;
        atomicAdd(&sacc[rep][0*K_+inst], cex);
        atomicAdd(&sacc[rep][1*K_+inst], cey);
        atomicAdd(&sacc[rep][2*K_+inst], cez);
        atomicAdd(&sacc[rep][3*K_+inst], e.w);
        atomicAdd(&sacc[rep][4*K_+inst], 1.0f);
    }
    __syncthreads();
    if (tid < 5*K_) {
        float a = sacc[0][tid] + sacc[1][tid] + sacc[2][tid] + sacc[3][tid];
        ws[ACC_OFF + tid*NBLK + g] = a;      // transposed: row t, col g
    }

    __threadfence();
    grid.sync();
    __threadfence();

    // ================= phase 2: finalize ONCE (blocks 0..3, one per batch) ==
    if (g < B_ && tid < 5*K_) {
        const float4* row = (const float4*)(ws + ACC_OFF + (size_t)tid*NBLK + g*BPB);
        float4 a4 = make_float4(0.f,0.f,0.f,0.f);
        #pragma unroll
        for (int j = 0; j < BPB/4; ++j) {
            float4 v = row[j];
            a4.x += v.x; a4.y += v.y; a4.z += v.z; a4.w += v.w;
        }
        s_raw[tid] = (a4.x + a4.y) + (a4.z + a4.w);
    }
    __syncthreads();
    if (g < B_ && tid < K_) {
        float cnt = fmaxf(s_raw[4*K_+tid], 1.f);
        float inv = 1.f / cnt;
        float cx = s_raw[0*K_+tid] * inv;
        float cy = s_raw[1*K_+tid] * inv;
        float cz = s_raw[2*K_+tid] * inv;
        float sg = s_raw[3*K_+tid] * inv;
        float i2s = 1.f / (2.f*sg*sg);
        float* fin = ws + FIN_OFF;
        fin[0*BK_ + g*K_+tid] = cx;
        fin[1*BK_ + g*K_+tid] = cy;
        fin[2*BK_ + g*K_+tid] = cz;
        fin[3*BK_ + g*K_+tid] = sg;
        fin[4*BK_ + g*K_+tid] = inv;
        fin[5*BK_ + g*K_+tid] = i2s;
    }

    __threadfence();
    grid.sync();
    __threadfence();

    // ================= phase 3: per-point pass =================
    {
        const float* fin = ws + FIN_OFF;
        if (tid < K_) {
            int idx = b*K_ + tid;
            s_c4[tid] = make_float4(fin[0*BK_+idx], fin[1*BK_+idx],
                                    fin[2*BK_+idx], fin[5*BK_+idx]);
            s_sig[tid] = fin[3*BK_+idx];
            s_inv[tid] = fin[4*BK_+idx];
        }
    }
    __syncthreads();

    float v0 = 0.f, v1 = 0.f, v2 = 0.f, v3 = 0.f;
    #pragma unroll
    for (int it = 0; it < PPB/NTHR; ++it) {
        int n = g*PPB + it*NTHR + tid;
        float4 e = emb[n];
        float sd = seedp[n];
        const float* lr = labels + (size_t)n*6;
        float c1 = lr[1];
        float2 c23 = *reinterpret_cast<const float2*>(lr + 2);
        int inst = ((int)lr[5]) & 31;
        float cex = e.x + (c1    - 384.f)/384.f;
        float cey = e.y + (c23.x - 384.f)/384.f;
        float cez = e.z + (c23.y - 384.f)/384.f;
        float sigma = e.w;

        unsigned bestpk = 0xffffffffu;
        float msum = 0.f;
        #pragma unroll
        for (int k = 0; k < K_; ++k) {
            float4 c = s_c4[k];             // one ds_read_b128, broadcast
            float dx = cex - c.x;
            float dy = cey - c.y;
            float dz = cez - c.z;
            float d2 = dx*dx + dy*dy + dz*dz;
            // packed argmin: d2>=0 so float bits order-preserve; low 5 bits carry k
            unsigned pk = (__float_as_uint(d2) & ~31u) | (unsigned)k;
            bestpk = min(bestpk, pk);
            float arg = d2 * c.w;
            // true log1p(-e^-arg) for arg>=15 is in (-3.2e-7,0]: contributes 0
            if (__any(arg < 15.f)) {
                float argc = fminf(fmaxf(arg, 1e-7f), 100.f);
                float p = __expf(-argc);
                float l1p = __logf(1.f - p);   // == log1p(-p), 1-p exact (Sterbenz)
                msum += (arg < 15.f) ? l1p : 0.f;
            }
        }
        int bi = (int)(bestpk & 31u);

        // k = inst term recomputed once
        float4 cI = s_c4[inst];
        float dxI = cex - cI.x;
        float dyI = cey - cI.y;
        float dzI = cez - cI.z;
        float d2I = dxI*dxI + dyI*dyI + dzI*dzI;
        float argRawI = d2I * cI.w;
        float argI = fminf(fmaxf(argRawI, 1e-7f), 100.f);
        float pI = __expf(-argI);
        if (argRawI < 15.f) msum -= __logf(1.f - pI);  // undo its l1p
        msum -= argI;                                   // onehot * (-arg)

        float inv_in = s_inv[inst];
        v0 += msum;
        v1 += fabsf(sigma - s_sig[inst]) * inv_in;
        float dsd = sd - pI;
        v2 += dsd*dsd*inv_in;
        v3 += (bi == inst) ? 1.0f : 0.0f;
    }

    // block reduction: wave shuffle then cross-wave via LDS (16 waves)
    for (int off = 32; off; off >>= 1) {
        v0 += __shfl_down(v0, off);
        v1 += __shfl_down(v1, off);
        v2 += __shfl_down(v2, off);
        v3 += __shfl_down(v3, off);
    }
    int wid = tid >> 6, lane = tid & 63;
    if (lane == 0) { sred[wid][0]=v0; sred[wid][1]=v1; sred[wid][2]=v2; sred[wid][3]=v3; }
    __syncthreads();
    if (tid == 0) {
        float r0=0.f,r1=0.f,r2=0.f,r3=0.f;
        for (int w = 0; w < 16; ++w) { r0+=sred[w][0]; r1+=sred[w][1]; r2+=sred[w][2]; r3+=sred[w][3]; }
        ((float4*)(ws + PART_OFF))[g] = make_float4(r0, r1, r2, r3);
    }

    __threadfence();
    grid.sync();
    __threadfence();

    // ================= phase 4: final reduce (block 0 only) =================
    if (g != 0) return;

    const float* pf = ws + PART_OFF;
    // 16 (f,batch) pairs, 64 lanes each: lane j sums part[bb*64+j][f]
    int pair = tid >> 6;          // 0..15
    int f = pair >> 2, bb0 = pair & 3;
    float v = pf[(bb0*BPB + lane)*4 + f];
    for (int off = 32; off; off >>= 1) v += __shfl_down(v, off);
    if (lane == 0) S[pair] = v;

    // inter-loss hinge over center pairs (4096 over 1024 threads)
    const float* fin = ws + FIN_OFF;
    float h = 0.f;
    for (int idx = tid; idx < B_*K_*K_; idx += NTHR) {
        int bb = idx >> 10;
        int ij = idx & 1023;
        int i = ij >> 5, j = ij & 31;
        if (i != j) {
            float dx = fin[0*BK_ + bb*K_+i] - fin[0*BK_ + bb*K_+j];
            float dy = fin[1*BK_ + bb*K_+i] - fin[1*BK_ + bb*K_+j];
            float dz = fin[2*BK_ + bb*K_+i] - fin[2*BK_ + bb*K_+j];
            float cd2 = dx*dx + dy*dy + dz*dz;
            float d = sqrtf(cd2);
            float hg = fmaxf(0.f, 1.0f - d);
            h += hg*hg;
        }
    }
    for (int off = 32; off; off >>= 1) h += __shfl_down(h, off);
    __shared__ float sh[16];
    if (lane == 0) sh[wid] = h;
    __syncthreads();

    if (tid == 0) {
        float ht = 0.f;
        for (int w = 0; w < 16; ++w) ht += sh[w];
        float loss = 0.f;
        for (int bb = 0; bb < B_; ++bb) {
            float mask_l   = -S[0*4+bb] / (float)NB_ / (float)K_;
            float smooth_l =  S[1*4+bb] / (float)K_;
            float seed_l   =  S[2*4+bb] / (float)K_;
            loss += mask_l + smooth_l + seed_l;
        }
        loss = loss / (float)B_ + ht / (2.0f * (float)(K_*(K_-1)) * (float)B_);
        float acc = (S[3*4+0]+S[3*4+1]+S[3*4+2]+S[3*4+3]) / (float)N_;
        out[0] = loss;
        out[1] = acc;
    }
}

extern "C" void kernel_launch(void* const* d_in, const int* in_sizes, int n_in,
                              void* d_out, int out_size, void* d_ws, size_t ws_size,
                              hipStream_t stream)
{
    const float4* emb    = (const float4*)d_in[0];
    const float*  seedp  = (const float*)d_in[1];
    const float*  labels = (const float*)d_in[2];
    float* ws  = (float*)d_ws;
    float* out = (float*)d_out;

    void* args[] = { (void*)&emb, (void*)&seedp, (void*)&labels,
                     (void*)&ws, (void*)&out };
    dim3 grid(NBLK), block(NTHR);
    hipLaunchCooperativeKernel((const void*)k_all, grid, block, args, 0, stream);
}

// Round 11
// 46.629 us; speedup vs baseline: 11.0934x; 11.0934x over previous
//
#include <hip/hip_runtime.h>

#define B_ 4
#define NB_ 131072
#define K_ 32
#define N_ (B_*NB_)
#define BK_ (B_*K_)        // 128
#define NACC 256           // k_accum blocks (64 per batch)
#define ABLK 64            // accum blocks per batch
#define PTS_PER_ACC 2048   // points per accum block
#define NMAIN 256          // main blocks (1 per CU)
#define MPB   64           // main blocks per batch
#define NTHR  1024
#define PPT   8            // points per thread in main (1024*8*256 = N_... check: 256*1024*8 = 2097152 = 4*131072*4? N_=524288; 256*1024=262144*2=524288 -> PPT=2)

// NOTE: N_ = 524288; NMAIN*NTHR = 262144 -> 2 points per thread.
#undef PPT
#define PPT 2

// ws float layout (no zeroing needed except tickets, zeroed by k_accum):
//   acc  [NACC][5*K_]   : per-block partial sums, block-major (coalesced phase-A)
//   fin  [6][BK_]       : finalized cx,cy,cz,sig_mean,inv_cnt,inv2s2
//   part [NMAIN][4]     : per-block partials (msum,smooth,seed,acc)
//   bfin [B_][4]        : per-batch reduced partials
//   tick [5]            : tickets: [0..3] per-batch, [4] final
#define ACC_OFF  0
#define FIN_OFF  (NACC*5*K_)             // 40960
#define PART_OFF (FIN_OFF + 6*BK_)       // 41728
#define BFIN_OFF (PART_OFF + NMAIN*4)    // 42752
#define TICK_OFF (BFIN_OFF + B_*4)       // 42768

__global__ __launch_bounds__(1024) void k_accum(
    const float4* __restrict__ emb, const float* __restrict__ labels,
    float* __restrict__ ws)
{
    if (blockIdx.x == 0 && threadIdx.x < 5)
        ((unsigned*)(ws + TICK_OFF))[threadIdx.x] = 0u;

    __shared__ float sacc[5*K_];
    int tid = threadIdx.x;
    if (tid < 5*K_) sacc[tid] = 0.f;
    __syncthreads();
    int start = blockIdx.x * PTS_PER_ACC;
    #pragma unroll
    for (int i = 0; i < PTS_PER_ACC/1024; ++i) {
        int n = start + i*1024 + tid;
        float4 e = emb[n];
        const float* lr = labels + (size_t)n*6;
        float c1 = lr[1];
        float2 c23 = *reinterpret_cast<const float2*>(lr + 2);
        int inst = ((int)lr[5]) & 31;
        float cex = e.x + (c1    - 384.f)/384.f;
        float cey = e.y + (c23.x - 384.f)/384.f;
        float cez = e.z + (c23.y - 384.f)/384.f;
        atomicAdd(&sacc[0*K_+inst], cex);
        atomicAdd(&sacc[1*K_+inst], cey);
        atomicAdd(&sacc[2*K_+inst], cez);
        atomicAdd(&sacc[3*K_+inst], e.w);
        atomicAdd(&sacc[4*K_+inst], 1.0f);
    }
    __syncthreads();
    // block-major plain store: phase-A reads ws[b*ABLK*160 + j*160 + t] coalesced over t
    if (tid < 5*K_) ws[ACC_OFF + blockIdx.x*5*K_ + tid] = sacc[tid];
}

__global__ __launch_bounds__(1024) void k_main2(
    const float4* __restrict__ emb, const float* __restrict__ seedp,
    const float* __restrict__ labels, float* __restrict__ ws,
    float* __restrict__ out)
{
    __shared__ float s_raw[5*K_];
    __shared__ float4 s_c4[K_];      // {cx,cy,cz,inv2s2}
    __shared__ float s_sig[K_], s_inv[K_];
    __shared__ float sred[16][4];
    __shared__ unsigned s_flag;
    int tid = threadIdx.x;
    int g = blockIdx.x;
    int b = g >> 6;                  // 64 main blocks per batch
    int wid = tid >> 6, lane = tid & 63;
    float4* part = (float4*)(ws + PART_OFF);
    float* bfin = ws + BFIN_OFF;
    unsigned* tick = (unsigned*)(ws + TICK_OFF);

    // ---- phase A: per-block redundant finalize (coalesced, r7 layout) ----
    if (tid < 5*K_) {
        float a = 0.f;
        const float* base = ws + ACC_OFF + (size_t)b*ABLK*5*K_ + tid;
        #pragma unroll 8
        for (int j = 0; j < ABLK; ++j) a += base[(size_t)j*5*K_];
        s_raw[tid] = a;
    }
    __syncthreads();
    if (tid < K_) {
        float cnt = fmaxf(s_raw[4*K_+tid], 1.f);
        float inv = 1.f / cnt;
        float cx = s_raw[0*K_+tid] * inv;
        float cy = s_raw[1*K_+tid] * inv;
        float cz = s_raw[2*K_+tid] * inv;
        float sg = s_raw[3*K_+tid] * inv;
        float i2s = 1.f / (2.f*sg*sg);
        s_c4[tid] = make_float4(cx, cy, cz, i2s);
        s_sig[tid] = sg;
        s_inv[tid] = inv;
        if ((g & 63) == 0) {             // one block per batch persists fin
            float* fin = ws + FIN_OFF;
            fin[0*BK_ + b*K_+tid] = cx;
            fin[1*BK_ + b*K_+tid] = cy;
            fin[2*BK_ + b*K_+tid] = cz;
            fin[3*BK_ + b*K_+tid] = sg;
            fin[4*BK_ + b*K_+tid] = inv;
            fin[5*BK_ + b*K_+tid] = i2s;
        }
    }
    __syncthreads();

    // ---- phase B: per-point pass (2 points/thread) ----
    float v0 = 0.f, v1 = 0.f, v2 = 0.f, v3 = 0.f;
    #pragma unroll
    for (int it = 0; it < PPT; ++it) {
        int n = (b*MPB + (g & 63))* (MPB==64 ? 0 : 0) /*dummy*/ + 0;
        n = g*(NTHR*PPT) + it*NTHR + tid;
        float4 e = emb[n];
        float sd = seedp[n];
        const float* lr = labels + (size_t)n*6;
        float c1 = lr[1];
        float2 c23 = *reinterpret_cast<const float2*>(lr + 2);
        int inst = ((int)lr[5]) & 31;
        float cex = e.x + (c1    - 384.f)/384.f;
        float cey = e.y + (c23.x - 384.f)/384.f;
        float cez = e.z + (c23.y - 384.f)/384.f;
        float sigma = e.w;

        unsigned bestpk = 0xffffffffu;
        float msum = 0.f;
        #pragma unroll
        for (int k = 0; k < K_; ++k) {
            float4 c = s_c4[k];             // ds_read_b128 broadcast
            float dx = cex - c.x;
            float dy = cey - c.y;
            float dz = cez - c.z;
            float d2 = dx*dx + dy*dy + dz*dz;
            // packed argmin: d2>=0 -> float bits order-preserve; low 5 bits carry k
            unsigned pk = (__float_as_uint(d2) & ~31u) | (unsigned)k;
            bestpk = min(bestpk, pk);
            float arg = d2 * c.w;
            // true log1p(-e^-arg) for arg>=15 is in (-3.2e-7,0]: contributes 0
            if (__any(arg < 15.f)) {
                float argc = fminf(fmaxf(arg, 1e-7f), 100.f);
                float p = __expf(-argc);
                float l1p = __logf(1.f - p);   // == log1p(-p), 1-p exact (Sterbenz)
                msum += (arg < 15.f) ? l1p : 0.f;
            }
        }
        int bi = (int)(bestpk & 31u);

        // k = inst term recomputed once
        float4 cI = s_c4[inst];
        float dxI = cex - cI.x;
        float dyI = cey - cI.y;
        float dzI = cez - cI.z;
        float d2I = dxI*dxI + dyI*dyI + dzI*dzI;
        float argRawI = d2I * cI.w;
        float argI = fminf(fmaxf(argRawI, 1e-7f), 100.f);
        float pI = __expf(-argI);
        if (argRawI < 15.f) msum -= __logf(1.f - pI);  // undo its l1p
        msum -= argI;                                   // onehot * (-arg)

        float inv_in = s_inv[inst];
        v0 += msum;
        v1 += fabsf(sigma - s_sig[inst]) * inv_in;
        float dsd = sd - pI;
        v2 += dsd*dsd*inv_in;
        v3 += (bi == inst) ? 1.0f : 0.0f;
    }

    // block reduction: wave shuffle then cross-wave via LDS (16 waves)
    for (int off = 32; off; off >>= 1) {
        v0 += __shfl_down(v0, off);
        v1 += __shfl_down(v1, off);
        v2 += __shfl_down(v2, off);
        v3 += __shfl_down(v3, off);
    }
    if (lane == 0) { sred[wid][0]=v0; sred[wid][1]=v1; sred[wid][2]=v2; sred[wid][3]=v3; }
    __syncthreads();
    if (tid == 0) {
        float r0=0.f,r1=0.f,r2=0.f,r3=0.f;
        for (int w = 0; w < 16; ++w) { r0+=sred[w][0]; r1+=sred[w][1]; r2+=sred[w][2]; r3+=sred[w][3]; }
        part[g] = make_float4(r0, r1, r2, r3);
        __threadfence();                       // release part[g]
        s_flag = (atomicAdd(&tick[b], 1u) == MPB-1u) ? 1u : 0u;
    }
    __syncthreads();

    // ---- batch-last block: reduce this batch's 64 partials ----
    if (s_flag) {
        __threadfence();                       // acquire all part[] of batch b
        if (wid < 4) {                         // wave f reduces component f
            float v = ((const float*)part)[(b*MPB + lane)*4 + wid];
            for (int off = 32; off; off >>= 1) v += __shfl_down(v, off);
            if (lane == 0) bfin[b*4 + wid] = v;
        }
        __syncthreads();
        if (tid == 0) {
            __threadfence();                   // release bfin[b]
            s_flag = (atomicAdd(&tick[4], 1u) == B_-1u) ? 2u : 0u;
        }
        __syncthreads();
    }

    // ---- very last block: hinge + combine + output ----
    if (s_flag != 2u) return;
    __threadfence();                           // acquire bfin[], fin[]

    const float* fin = ws + FIN_OFF;
    float h = 0.f;
    for (int idx = tid; idx < B_*K_*K_; idx += NTHR) {
        int bb = idx >> 10;
        int ij = idx & 1023;
        int i = ij >> 5, j = ij & 31;
        if (i != j) {
            float dx = fin[0*BK_ + bb*K_+i] - fin[0*BK_ + bb*K_+j];
            float dy = fin[1*BK_ + bb*K_+i] - fin[1*BK_ + bb*K_+j];
            float dz = fin[2*BK_ + bb*K_+i] - fin[2*BK_ + bb*K_+j];
            float cd2 = dx*dx + dy*dy + dz*dz;
            float d = sqrtf(cd2);
            float hg = fmaxf(0.f, 1.0f - d);
            h += hg*hg;
        }
    }
    for (int off = 32; off; off >>= 1) h += __shfl_down(h, off);
    __shared__ float sh[16];
    if (lane == 0) sh[wid] = h;
    __syncthreads();

    if (tid == 0) {
        float ht = 0.f;
        for (int w = 0; w < 16; ++w) ht += sh[w];
        float loss = 0.f;
        for (int bb = 0; bb < B_; ++bb) {
            float mask_l   = -bfin[bb*4+0] / (float)NB_ / (float)K_;
            float smooth_l =  bfin[bb*4+1] / (float)K_;
            float seed_l   =  bfin[bb*4+2] / (float)K_;
            loss += mask_l + smooth_l + seed_l;
        }
        loss = loss / (float)B_ + ht / (2.0f * (float)(K_*(K_-1)) * (float)B_);
        float acc = (bfin[0*4+3]+bfin[1*4+3]+bfin[2*4+3]+bfin[3*4+3]) / (float)N_;
        out[0] = loss;
        out[1] = acc;
    }
}

extern "C" void kernel_launch(void* const* d_in, const int* in_sizes, int n_in,
                              void* d_out, int out_size, void* d_ws, size_t ws_size,
                              hipStream_t stream)
{
    const float4* emb    = (const float4*)d_in[0];
    const float*  seedp  = (const float*)d_in[1];
    const float*  labels = (const float*)d_in[2];
    float* ws  = (float*)d_ws;
    float* out = (float*)d_out;

    // 2 dispatches; tickets zeroed by k_accum block 0 (stream order)
    k_accum <<<NACC,  NTHR, 0, stream>>>(emb, labels, ws);
    k_main2 <<<NMAIN, NTHR, 0, stream>>>(emb, seedp, labels, ws, out);
}

// Round 12
// 46.228 us; speedup vs baseline: 11.1895x; 1.0087x over previous
//
#include <hip/hip_runtime.h>

#define B_ 4
#define NB_ 131072
#define K_ 32
#define N_ (B_*NB_)
#define BK_ (B_*K_)        // 128
#define NACC 256           // k_accum blocks (64 per batch)
#define ABLK 64            // accum blocks per batch
#define PTS_PER_ACC 2048   // points per accum block

// ws float layout (no zeroing needed anywhere — every slot is plain-stored):
//   acc  [NACC][5*K_]   : per-block partial sums (cx,cy,cz,sig,cnt)
//   fin  [6][BK_]       : finalized cx,cy,cz,sig_mean,inv_cnt,inv2s2
//   part [2048][4]      : per-block partials from k_main
#define ACC_OFF  0
#define FIN_OFF  (NACC*5*K_)             // 40960
#define PART_OFF (FIN_OFF + 6*BK_)       // 41728

__global__ __launch_bounds__(1024) void k_accum(
    const float4* __restrict__ emb, const float* __restrict__ labels,
    float* __restrict__ ws)
{
    __shared__ float sacc[5*K_];
    int tid = threadIdx.x;
    if (tid < 5*K_) sacc[tid] = 0.f;
    __syncthreads();
    int start = blockIdx.x * PTS_PER_ACC;
    #pragma unroll
    for (int i = 0; i < PTS_PER_ACC/1024; ++i) {
        int n = start + i*1024 + tid;
        float4 e = emb[n];
        const float* lr = labels + (size_t)n*6;
        float c1 = lr[1];
        float2 c23 = *reinterpret_cast<const float2*>(lr + 2);
        int inst = ((int)lr[5]) & 31;
        float cex = e.x + (c1    - 384.f)/384.f;
        float cey = e.y + (c23.x - 384.f)/384.f;
        float cez = e.z + (c23.y - 384.f)/384.f;
        atomicAdd(&sacc[0*K_+inst], cex);
        atomicAdd(&sacc[1*K_+inst], cey);
        atomicAdd(&sacc[2*K_+inst], cez);
        atomicAdd(&sacc[3*K_+inst], e.w);
        atomicAdd(&sacc[4*K_+inst], 1.0f);
    }
    __syncthreads();
    // plain store of this block's 160 partials (no atomics, no pre-zero)
    if (tid < 5*K_) ws[ACC_OFF + blockIdx.x*5*K_ + tid] = sacc[tid];
}

__global__ __launch_bounds__(256) void k_main(
    const float4* __restrict__ emb, const float* __restrict__ seedp,
    const float* __restrict__ labels, float* __restrict__ ws,
    float4* __restrict__ part)
{
    __shared__ float s_raw[5*K_];
    __shared__ float s_cx[K_], s_cy[K_], s_cz[K_], s_sig[K_], s_inv[K_], s_i2s[K_];
    int tid = threadIdx.x;
    int n = blockIdx.x * 256 + tid;
    int b = blockIdx.x >> 9;         // 512 blocks per batch

    // ---- phase A: per-block redundant finalize of this batch's partials ----
    if (tid < 5*K_) {
        float a = 0.f;
        const float* base = ws + ACC_OFF + (size_t)b*ABLK*5*K_ + tid;
        #pragma unroll 8
        for (int j = 0; j < ABLK; ++j) a += base[(size_t)j*5*K_];
        s_raw[tid] = a;
    }
    __syncthreads();
    if (tid < K_) {
        float cnt = fmaxf(s_raw[4*K_+tid], 1.f);
        float inv = 1.f / cnt;
        float cx = s_raw[0*K_+tid] * inv;
        float cy = s_raw[1*K_+tid] * inv;
        float cz = s_raw[2*K_+tid] * inv;
        float sg = s_raw[3*K_+tid] * inv;
        float i2s = 1.f / (2.f*sg*sg);
        s_cx[tid] = cx;  s_cy[tid] = cy;  s_cz[tid] = cz;
        s_sig[tid] = sg; s_inv[tid] = inv; s_i2s[tid] = i2s;
        if ((blockIdx.x & 511) == 0) {      // one block per batch persists fin
            float* fin = ws + FIN_OFF;
            fin[0*BK_ + b*K_+tid] = cx;
            fin[1*BK_ + b*K_+tid] = cy;
            fin[2*BK_ + b*K_+tid] = cz;
            fin[3*BK_ + b*K_+tid] = sg;
            fin[4*BK_ + b*K_+tid] = inv;
            fin[5*BK_ + b*K_+tid] = i2s;
        }
    }
    __syncthreads();

    // ---- phase B: per-point pass ----
    float4 e = emb[n];
    float sd = seedp[n];
    const float* lr = labels + (size_t)n*6;
    float c1 = lr[1];
    float2 c23 = *reinterpret_cast<const float2*>(lr + 2);
    int inst = ((int)lr[5]) & 31;
    float cex = e.x + (c1    - 384.f)/384.f;
    float cey = e.y + (c23.x - 384.f)/384.f;
    float cez = e.z + (c23.y - 384.f)/384.f;
    float sigma = e.w;

    // tight branch-free loop: argmin + min-arg only (log terms are ~always 0)
    unsigned bestpk = 0xffffffffu;
    float minarg = 3.4e38f;
    #pragma unroll
    for (int k = 0; k < K_; ++k) {
        float dx = cex - s_cx[k];
        float dy = cey - s_cy[k];
        float dz = cez - s_cz[k];
        float d2 = dx*dx + dy*dy + dz*dz;
        // packed argmin: d2>=0 so float bits are order-preserving; low 5 bits
        // carry k so exact ties resolve to the first (lowest-k) min like jnp.argmin
        unsigned pk = (__float_as_uint(d2) & ~31u) | (unsigned)k;
        bestpk = min(bestpk, pk);
        minarg = fminf(minarg, d2 * s_i2s[k]);
    }
    int bi = (int)(bestpk & 31u);

    // rare exact fallback: |log1p(-e^-arg)| < 6e-8 for arg>=17 -> those terms are 0.
    // minarg >= 17 for every lane (typical: arg ~ 2000*d2) -> skip entirely.
    float msum = 0.f;
    if (__any(minarg < 17.f)) {
        #pragma unroll 4
        for (int k = 0; k < K_; ++k) {
            float dx = cex - s_cx[k];
            float dy = cey - s_cy[k];
            float dz = cez - s_cz[k];
            float d2 = dx*dx + dy*dy + dz*dz;
            float arg = d2 * s_i2s[k];
            if (arg < 17.f) {
                float argc = fmaxf(arg, 1e-7f);          // (<17 so hi-clip moot)
                float p = __expf(-argc);
                msum += __logf(1.f - p);                 // == log1p(-p) (Sterbenz)
            }
        }
    }

    // k = inst term, recomputed once
    float dxI = cex - s_cx[inst];
    float dyI = cey - s_cy[inst];
    float dzI = cez - s_cz[inst];
    float d2I = dxI*dxI + dyI*dyI + dzI*dzI;
    float argRawI = d2I * s_i2s[inst];
    float argI = fminf(fmaxf(argRawI, 1e-7f), 100.f);
    float pI = __expf(-argI);
    if (argRawI < 17.f) msum -= __logf(1.f - pI);   // undo its term from fallback
    msum -= argI;                                    // onehot * (-arg)

    float inv_in = s_inv[inst];
    float smoothv = fabsf(sigma - s_sig[inst]) * inv_in;
    float dsd = sd - pI;
    float seedv = dsd*dsd*inv_in;
    float accv = (bi == inst) ? 1.0f : 0.0f;

    // block reduction: wave shuffle then cross-wave via LDS
    float v0 = msum, v1 = smoothv, v2 = seedv, v3 = accv;
    for (int off = 32; off; off >>= 1) {
        v0 += __shfl_down(v0, off);
        v1 += __shfl_down(v1, off);
        v2 += __shfl_down(v2, off);
        v3 += __shfl_down(v3, off);
    }
    __shared__ float sred[4][4];
    int wid = tid >> 6, lane = tid & 63;
    if (lane == 0) { sred[wid][0]=v0; sred[wid][1]=v1; sred[wid][2]=v2; sred[wid][3]=v3; }
    __syncthreads();
    if (tid == 0) {
        float r0=0.f,r1=0.f,r2=0.f,r3=0.f;
        for (int w = 0; w < 4; ++w) { r0+=sred[w][0]; r1+=sred[w][1]; r2+=sred[w][2]; r3+=sred[w][3]; }
        part[blockIdx.x] = make_float4(r0, r1, r2, r3);   // plain store, no atomics
    }
}

__global__ __launch_bounds__(256) void k_final(
    const float* __restrict__ ws, const float* __restrict__ part,
    float* __restrict__ out)
{
    int tid = threadIdx.x;

    // --- reduce per-block partials: 16 (f,b) pairs, 16 threads each ---
    int pair = tid >> 4;          // 0..15
    int lane16 = tid & 15;
    int f = pair >> 2, b = pair & 3;
    float v = 0.f;
    #pragma unroll
    for (int j = 0; j < 32; ++j) {
        int blk = b*512 + lane16*32 + j;
        v += part[blk*4 + f];
    }
    v += __shfl_down(v, 8);
    v += __shfl_down(v, 4);
    v += __shfl_down(v, 2);
    v += __shfl_down(v, 1);
    __shared__ float S[16];       // S[f*4+b]
    if (lane16 == 0) S[pair] = v;

    // --- inter-loss hinge over center pairs ---
    float h = 0.f;
    for (int idx = tid; idx < B_*K_*K_; idx += 256) {
        int bb = idx >> 10;
        int ij = idx & 1023;
        int i = ij >> 5, j = ij & 31;
        if (i != j) {
            const float* fin = ws + FIN_OFF;
            float dx = fin[0*BK_ + bb*K_+i] - fin[0*BK_ + bb*K_+j];
            float dy = fin[1*BK_ + bb*K_+i] - fin[1*BK_ + bb*K_+j];
            float dz = fin[2*BK_ + bb*K_+i] - fin[2*BK_ + bb*K_+j];
            float cd2 = dx*dx + dy*dy + dz*dz;
            float d = sqrtf(cd2);
            float hg = fmaxf(0.f, 1.0f - d);
            h += hg*hg;
        }
    }
    for (int off = 32; off; off >>= 1) h += __shfl_down(h, off);
    __shared__ float sh[4];
    int wid = tid >> 6, lane = tid & 63;
    if (lane == 0) sh[wid] = h;
    __syncthreads();

    if (tid == 0) {
        float ht = sh[0]+sh[1]+sh[2]+sh[3];
        float loss = 0.f;
        for (int bb = 0; bb < B_; ++bb) {
            float mask_l   = -S[0*4+bb] / (float)NB_ / (float)K_;
            float smooth_l =  S[1*4+bb] / (float)K_;
            float seed_l   =  S[2*4+bb] / (float)K_;
            loss += mask_l + smooth_l + seed_l;
        }
        loss = loss / (float)B_ + ht / (2.0f * (float)(K_*(K_-1)) * (float)B_);
        float acc = (S[3*4+0]+S[3*4+1]+S[3*4+2]+S[3*4+3]) / (float)N_;
        out[0] = loss;
        out[1] = acc;
    }
}

extern "C" void kernel_launch(void* const* d_in, const int* in_sizes, int n_in,
                              void* d_out, int out_size, void* d_ws, size_t ws_size,
                              hipStream_t stream)
{
    const float4* emb    = (const float4*)d_in[0];
    const float*  seedp  = (const float*)d_in[1];
    const float*  labels = (const float*)d_in[2];
    float* ws  = (float*)d_ws;
    float* out = (float*)d_out;

    // 3 dispatches; no memset needed (all ws regions fully written by plain stores)
    k_accum <<<NACC,   1024, 0, stream>>>(emb, labels, ws);
    k_main  <<<N_/256, 256,  0, stream>>>(emb, seedp, labels, ws,
                                          (float4*)(ws + PART_OFF));
    k_final <<<1,      256,  0, stream>>>(ws, ws + PART_OFF, out);
}

// Round 13
// 44.753 us; speedup vs baseline: 11.5584x; 1.0330x over previous
//
#include <hip/hip_runtime.h>

#define B_ 4
#define NB_ 131072
#define K_ 32
#define N_ (B_*NB_)
#define BK_ (B_*K_)        // 128
#define NACC 256           // k_accum blocks (64 per batch)
#define ABLK 64            // accum blocks per batch
#define PTS_PER_ACC 2048   // points per accum block

// ws float layout (no zeroing needed; every slot plain-stored each call):
//   acc  [NACC][5*K_]   : per-block partial sums (cx,cy,cz,sig,cnt)
//   fin  [6][BK_]       : finalized cx,cy,cz,sig_mean,inv_cnt,inv2s2
//   part [2048][4]      : per-block partials from k_main
//   pk   [N_] float4    : packed per-point {cex,cey,cez,sigma}
//   inst8[N_] uchar     : per-point cluster id
#define ACC_OFF  0
#define FIN_OFF  (NACC*5*K_)             // 40960
#define PART_OFF (FIN_OFF + 6*BK_)       // 41728
#define PK_OFF   49920                   // float4-aligned (49920*4 % 16 == 0)
#define INST_OFF (PK_OFF + N_*4)         // 2147072 (floats); uchar region

__global__ __launch_bounds__(1024) void k_accum(
    const float4* __restrict__ emb, const float* __restrict__ labels,
    float* __restrict__ ws)
{
    float4* pk = (float4*)(ws + PK_OFF);
    unsigned char* inst8 = (unsigned char*)(ws + INST_OFF);
    __shared__ float sacc[5*K_];
    int tid = threadIdx.x;
    if (tid < 5*K_) sacc[tid] = 0.f;
    __syncthreads();
    int start = blockIdx.x * PTS_PER_ACC;
    #pragma unroll
    for (int i = 0; i < PTS_PER_ACC/1024; ++i) {
        int n = start + i*1024 + tid;
        float4 e = emb[n];
        const float* lr = labels + (size_t)n*6;
        float c1 = lr[1];
        float2 c23 = *reinterpret_cast<const float2*>(lr + 2);
        int inst = ((int)lr[5]) & 31;
        float cex = e.x + (c1    - 384.f)/384.f;
        float cey = e.y + (c23.x - 384.f)/384.f;
        float cez = e.z + (c23.y - 384.f)/384.f;
        pk[n] = make_float4(cex, cey, cez, e.w);   // packed record for pass 2
        inst8[n] = (unsigned char)inst;
        atomicAdd(&sacc[0*K_+inst], cex);
        atomicAdd(&sacc[1*K_+inst], cey);
        atomicAdd(&sacc[2*K_+inst], cez);
        atomicAdd(&sacc[3*K_+inst], e.w);
        atomicAdd(&sacc[4*K_+inst], 1.0f);
    }
    __syncthreads();
    if (tid < 5*K_) ws[ACC_OFF + blockIdx.x*5*K_ + tid] = sacc[tid];
}

__global__ __launch_bounds__(256) void k_finalize(float* __restrict__ ws)
{
    int b = blockIdx.x;              // one block per batch
    int tid = threadIdx.x;
    __shared__ float s_raw[5*K_];
    if (tid < 5*K_) {
        float a = 0.f;
        const float* base = ws + ACC_OFF + (size_t)b*ABLK*5*K_ + tid;
        #pragma unroll 8
        for (int j = 0; j < ABLK; ++j) a += base[(size_t)j*5*K_];
        s_raw[tid] = a;
    }
    __syncthreads();
    if (tid < K_) {
        float cnt = fmaxf(s_raw[4*K_+tid], 1.f);
        float inv = 1.f / cnt;
        float cx = s_raw[0*K_+tid] * inv;
        float cy = s_raw[1*K_+tid] * inv;
        float cz = s_raw[2*K_+tid] * inv;
        float sg = s_raw[3*K_+tid] * inv;
        float i2s = 1.f / (2.f*sg*sg);
        float* fin = ws + FIN_OFF;
        fin[0*BK_ + b*K_+tid] = cx;
        fin[1*BK_ + b*K_+tid] = cy;
        fin[2*BK_ + b*K_+tid] = cz;
        fin[3*BK_ + b*K_+tid] = sg;
        fin[4*BK_ + b*K_+tid] = inv;
        fin[5*BK_ + b*K_+tid] = i2s;
    }
}

__global__ __launch_bounds__(256) void k_main(
    const float4* __restrict__ emb, const float* __restrict__ seedp,
    const float* __restrict__ labels, float* __restrict__ ws,
    float4* __restrict__ part)
{
    __shared__ float s_all[6*K_];    // [f][k]: cx,cy,cz,sig,inv,i2s
    int tid = threadIdx.x;
    int n = blockIdx.x * 256 + tid;
    int b = blockIdx.x >> 9;         // 512 blocks per batch
    const float4* pk = (const float4*)(ws + PK_OFF);
    const unsigned char* inst8 = (const unsigned char*)(ws + INST_OFF);

    // phase A': one coalesced read of this batch's 192 finalized values
    if (tid < 6*K_) {
        int f = tid >> 5, k = tid & 31;
        s_all[tid] = ws[FIN_OFF + f*BK_ + b*K_ + k];
    }
    __syncthreads();
    const float* s_cx  = s_all + 0*K_;
    const float* s_cy  = s_all + 1*K_;
    const float* s_cz  = s_all + 2*K_;
    const float* s_sig = s_all + 3*K_;
    const float* s_inv = s_all + 4*K_;
    const float* s_i2s = s_all + 5*K_;

    // ---- phase B: per-point pass (dense loads only) ----
    float4 p4 = pk[n];
    float sd = seedp[n];
    int inst = (int)inst8[n];
    float cex = p4.x, cey = p4.y, cez = p4.z, sigma = p4.w;

    // tight branch-free loop: argmin + min-arg only (log terms are ~always 0)
    unsigned bestpk = 0xffffffffu;
    float minarg = 3.4e38f;
    #pragma unroll
    for (int k = 0; k < K_; ++k) {
        float dx = cex - s_cx[k];
        float dy = cey - s_cy[k];
        float dz = cez - s_cz[k];
        float d2 = dx*dx + dy*dy + dz*dz;
        // packed argmin: d2>=0 so float bits are order-preserving; low 5 bits
        // carry k so exact ties resolve to the first (lowest-k) min like jnp.argmin
        unsigned pkb = (__float_as_uint(d2) & ~31u) | (unsigned)k;
        bestpk = min(bestpk, pkb);
        minarg = fminf(minarg, d2 * s_i2s[k]);
    }
    int bi = (int)(bestpk & 31u);

    // rare exact fallback: |log1p(-e^-arg)| < 6e-8 for arg>=17 -> those terms are 0
    float msum = 0.f;
    if (__any(minarg < 17.f)) {
        #pragma unroll 4
        for (int k = 0; k < K_; ++k) {
            float dx = cex - s_cx[k];
            float dy = cey - s_cy[k];
            float dz = cez - s_cz[k];
            float d2 = dx*dx + dy*dy + dz*dz;
            float arg = d2 * s_i2s[k];
            if (arg < 17.f) {
                float argc = fmaxf(arg, 1e-7f);
                float p = __expf(-argc);
                msum += __logf(1.f - p);             // == log1p(-p) (Sterbenz)
            }
        }
    }

    // k = inst term, recomputed once
    float dxI = cex - s_cx[inst];
    float dyI = cey - s_cy[inst];
    float dzI = cez - s_cz[inst];
    float d2I = dxI*dxI + dyI*dyI + dzI*dzI;
    float argRawI = d2I * s_i2s[inst];
    float argI = fminf(fmaxf(argRawI, 1e-7f), 100.f);
    float pI = __expf(-argI);
    if (argRawI < 17.f) msum -= __logf(1.f - pI);   // undo its term from fallback
    msum -= argI;                                    // onehot * (-arg)

    float inv_in = s_inv[inst];
    float smoothv = fabsf(sigma - s_sig[inst]) * inv_in;
    float dsd = sd - pI;
    float seedv = dsd*dsd*inv_in;
    float accv = (bi == inst) ? 1.0f : 0.0f;

    // block reduction: wave shuffle then cross-wave via LDS
    float v0 = msum, v1 = smoothv, v2 = seedv, v3 = accv;
    for (int off = 32; off; off >>= 1) {
        v0 += __shfl_down(v0, off);
        v1 += __shfl_down(v1, off);
        v2 += __shfl_down(v2, off);
        v3 += __shfl_down(v3, off);
    }
    __shared__ float sred[4][4];
    int wid = tid >> 6, lane = tid & 63;
    if (lane == 0) { sred[wid][0]=v0; sred[wid][1]=v1; sred[wid][2]=v2; sred[wid][3]=v3; }
    __syncthreads();
    if (tid == 0) {
        float r0=0.f,r1=0.f,r2=0.f,r3=0.f;
        for (int w = 0; w < 4; ++w) { r0+=sred[w][0]; r1+=sred[w][1]; r2+=sred[w][2]; r3+=sred[w][3]; }
        part[blockIdx.x] = make_float4(r0, r1, r2, r3);   // plain store, no atomics
    }
}

__global__ __launch_bounds__(256) void k_final(
    const float* __restrict__ ws, const float* __restrict__ part,
    float* __restrict__ out)
{
    int tid = threadIdx.x;

    // --- reduce per-block partials: 16 (f,b) pairs, 16 threads each ---
    int pair = tid >> 4;          // 0..15
    int lane16 = tid & 15;
    int f = pair >> 2, b = pair & 3;
    float v = 0.f;
    #pragma unroll
    for (int j = 0; j < 32; ++j) {
        int blk = b*512 + lane16*32 + j;
        v += part[blk*4 + f];
    }
    v += __shfl_down(v, 8);
    v += __shfl_down(v, 4);
    v += __shfl_down(v, 2);
    v += __shfl_down(v, 1);
    __shared__ float S[16];       // S[f*4+b]
    if (lane16 == 0) S[pair] = v;

    // --- inter-loss hinge over center pairs ---
    float h = 0.f;
    for (int idx = tid; idx < B_*K_*K_; idx += 256) {
        int bb = idx >> 10;
        int ij = idx & 1023;
        int i = ij >> 5, j = ij & 31;
        if (i != j) {
            const float* fin = ws + FIN_OFF;
            float dx = fin[0*BK_ + bb*K_+i] - fin[0*BK_ + bb*K_+j];
            float dy = fin[1*BK_ + bb*K_+i] - fin[1*BK_ + bb*K_+j];
            float dz = fin[2*BK_ + bb*K_+i] - fin[2*BK_ + bb*K_+j];
            float cd2 = dx*dx + dy*dy + dz*dz;
            float d = sqrtf(cd2);
            float hg = fmaxf(0.f, 1.0f - d);
            h += hg*hg;
        }
    }
    for (int off = 32; off; off >>= 1) h += __shfl_down(h, off);
    __shared__ float sh[4];
    int wid = tid >> 6, lane = tid & 63;
    if (lane == 0) sh[wid] = h;
    __syncthreads();

    if (tid == 0) {
        float ht = sh[0]+sh[1]+sh[2]+sh[3];
        float loss = 0.f;
        for (int bb = 0; bb < B_; ++bb) {
            float mask_l   = -S[0*4+bb] / (float)NB_ / (float)K_;
            float smooth_l =  S[1*4+bb] / (float)K_;
            float seed_l   =  S[2*4+bb] / (float)K_;
            loss += mask_l + smooth_l + seed_l;
        }
        loss = loss / (float)B_ + ht / (2.0f * (float)(K_*(K_-1)) * (float)B_);
        float acc = (S[3*4+0]+S[3*4+1]+S[3*4+2]+S[3*4+3]) / (float)N_;
        out[0] = loss;
        out[1] = acc;
    }
}

extern "C" void kernel_launch(void* const* d_in, const int* in_sizes, int n_in,
                              void* d_out, int out_size, void* d_ws, size_t ws_size,
                              hipStream_t stream)
{
    const float4* emb    = (const float4*)d_in[0];
    const float*  seedp  = (const float*)d_in[1];
    const float*  labels = (const float*)d_in[2];
    float* ws  = (float*)d_ws;
    float* out = (float*)d_out;

    // 4 dispatches; no memset needed (all ws regions fully written by plain stores)
    k_accum    <<<NACC,   1024, 0, stream>>>(emb, labels, ws);
    k_finalize <<<B_,     256,  0, stream>>>(ws);
    k_main     <<<N_/256, 256,  0, stream>>>(emb, seedp, labels, ws,
                                             (float4*)(ws + PART_OFF));
    k_final    <<<1,      256,  0, stream>>>(ws, ws + PART_OFF, out);
}